// Round 4
// baseline (792.212 us; speedup 1.0000x reference)
//
#include <hip/hip_runtime.h>
#include <stdint.h>
#include <math.h>

#define NROW 8192
// dims: IN=32, G=16, H1=32, H2=16, LSTM_HID = H2+G = 32 (code value; "48" comment in ref is stale)
// gates = 4*32 = 128, LSTM_IN = 112, l2+h vec = 144, L3_IN = 64
// out: actions[8192], h_out[8192*32] @ 8192, c_out[8192*32] @ 270336

// ---------------- workspace layout (floats, in d_ws) ----------------
constexpr size_t W_FP  = 0;                              // fwd partials [16][8192][32]
constexpr size_t W_GP  = W_FP  + (size_t)16*NROW*32;     // tr  partials [8][8192][32]
constexpr size_t W_RSP = W_GP  + (size_t)8*NROW*32;      // rowsum partials [16][8192]
constexpr size_t W_CSP = W_RSP + (size_t)16*NROW;        // colsum partials [8][8192]
constexpr size_t W_RS  = W_CSP + (size_t)8*NROW;         // rowsum [8192]
constexpr size_t W_CS  = W_RS  + NROW;                   // colsum [8192]
constexpr size_t W_V1  = W_CS  + NROW;                   // v1 [8192][32]
constexpr size_t W_V2  = W_V1  + (size_t)NROW*32;        // v2 [8192][16]
constexpr size_t W_U1  = W_V2  + (size_t)NROW*16;        // u1 [16]
constexpr size_t W_U2  = W_U1  + 16;                     // u2 [16]
constexpr size_t W_MLP = W_U2  + 16;                     // l1-mean partials [256][96]
constexpr size_t W_U2P = W_MLP + (size_t)256*96;         // u2 partials [512][16]
// total 6,930,464 floats = 26.4 MiB

__device__ __forceinline__ float leaky(float v) { return v >= 0.f ? v : 0.01f * v; }
__device__ __forceinline__ double leakyd(double v) { return v >= 0. ? v : 0.01 * v; }
__device__ __forceinline__ double sigd(double v) { return 1.0 / (1.0 + exp(-v)); }

// JAX threefry2x32 (20 rounds), key = (0, 42)
__device__ __forceinline__ void threefry(uint32_t x0, uint32_t x1, uint32_t& o0, uint32_t& o1) {
  const uint32_t ks0 = 0u, ks1 = 42u;
  const uint32_t ks2 = ks0 ^ ks1 ^ 0x1BD11BDAu;
  uint32_t ks[3] = {ks0, ks1, ks2};
  const int R0[4] = {13, 15, 26, 6};
  const int R1[4] = {17, 29, 16, 24};
  x0 += ks[0]; x1 += ks[1];
  #pragma unroll
  for (int g = 0; g < 5; ++g) {
    const int* R = (g & 1) ? R1 : R0;
    #pragma unroll
    for (int i = 0; i < 4; ++i) {
      x0 += x1;
      x1 = (x1 << R[i]) | (x1 >> (32 - R[i]));
      x1 ^= x0;
    }
    x0 += ks[(g + 1) % 3];
    x1 += ks[(g + 2) % 3] + (uint32_t)(g + 1);
  }
  o0 = x0; o1 = x1;
}

// ---------------- forward: Fp[kz] = adj[rows, krange] @ X ----------------
// grid (32, 16), block 256. 256 rows/block, k-range 512 (16 tiles of 32).
template <int C, bool SUMROW>
__global__ __launch_bounds__(256) void k_fwd(const float* __restrict__ adj,
                                             const float* __restrict__ X,
                                             float* __restrict__ Fp,
                                             float* __restrict__ rsP) {
  __shared__ float aT[32 * 256];
  __shared__ float Xs[32 * C];
  const int t = threadIdx.x;
  const int I0 = blockIdx.x * 256;
  const int kz = blockIdx.y;
  const int kbase = kz * 512;
  const int isub = t >> 6;
  const int rg = (t & 63) >> 2;
  const int cg = t & 3;
  const int c0 = 8 * cg;
  const int gr = isub * 16 + rg;
  const int gr4 = gr * 4;

  float acc[4][8];
  #pragma unroll
  for (int r = 0; r < 4; ++r)
    #pragma unroll
    for (int c = 0; c < 8; ++c) acc[r][c] = 0.f;
  float accRS[4] = {0.f, 0.f, 0.f, 0.f};

  const int si = t >> 3;   // stage: i-lane 0..31
  const int skq = t & 7;   // stage: k-quad 0..7

  for (int kt = 0; kt < 16; ++kt) {
    const int kb = kbase + kt * 32;
    #pragma unroll
    for (int it = 0; it < 8; ++it) {
      const int i = it * 32 + si;
      const float4 g4 = *(const float4*)&adj[(size_t)(I0 + i) * NROW + kb + 4 * skq];
      float v[4] = {g4.x, g4.y, g4.z, g4.w};
      #pragma unroll
      for (int j = 0; j < 4; ++j) aT[(4 * skq + j) * 256 + i] = v[j];
    }
    if (C == 32) {
      const int kk = t >> 3, c = (t & 7) * 4;
      *(float4*)&Xs[kk * 32 + c] = *(const float4*)&X[(size_t)(kb + kk) * 32 + c];
    } else {
      if (t < 128) {
        const int kk = t >> 2, c = (t & 3) * 4;
        *(float4*)&Xs[kk * 16 + c] = *(const float4*)&X[(size_t)(kb + kk) * 16 + c];
      }
    }
    __syncthreads();
    if (c0 < C) {
      #pragma unroll 8
      for (int k = 0; k < 32; ++k) {
        const float4 a4 = *(const float4*)&aT[k * 256 + gr4];
        const float4 xlo = *(const float4*)&Xs[k * C + c0];
        const float4 xhi = *(const float4*)&Xs[k * C + c0 + 4];
        const float av[4] = {a4.x, a4.y, a4.z, a4.w};
        const float xv[8] = {xlo.x, xlo.y, xlo.z, xlo.w, xhi.x, xhi.y, xhi.z, xhi.w};
        #pragma unroll
        for (int r = 0; r < 4; ++r) {
          #pragma unroll
          for (int c = 0; c < 8; ++c) acc[r][c] += av[r] * xv[c];
          if (SUMROW && cg == 0) accRS[r] += fabsf(av[r]);
        }
      }
    }
    __syncthreads();
  }
  const int row = I0 + gr4;
  if (c0 < C) {
    #pragma unroll
    for (int r = 0; r < 4; ++r) {
      float4 lo = {acc[r][0], acc[r][1], acc[r][2], acc[r][3]};
      float4 hi = {acc[r][4], acc[r][5], acc[r][6], acc[r][7]};
      *(float4*)&Fp[((size_t)kz * NROW + row + r) * 32 + c0] = lo;
      *(float4*)&Fp[((size_t)kz * NROW + row + r) * 32 + c0 + 4] = hi;
    }
  }
  if (SUMROW && cg == 0) {
    #pragma unroll
    for (int r = 0; r < 4; ++r) rsP[(size_t)kz * NROW + row + r] = accRS[r];
  }
}

// ---------------- transpose: Gp[ks] = adj[irange,:].T @ X ----------------
// grid (128, 8), block 256.
template <int C, bool SUMCOL>
__global__ __launch_bounds__(256) void k_tr(const float* __restrict__ adj,
                                            const float* __restrict__ X,
                                            float* __restrict__ Gp,
                                            float* __restrict__ csP) {
  __shared__ float Xs[64 * C];
  const int t = threadIdx.x;
  const int J0 = blockIdx.x * 64;
  const int ks = blockIdx.y;
  const int ibase = ks * 1024;
  const int jl = t & 63;
  const int cg = t >> 6;
  const int c0 = 8 * cg;
  float acc[8] = {0.f, 0.f, 0.f, 0.f, 0.f, 0.f, 0.f, 0.f};
  float accCS = 0.f;

  for (int ch = 0; ch < 16; ++ch) {
    const int i0 = ibase + ch * 64;
    if (C == 32) {
      #pragma unroll
      for (int it = 0; it < 2; ++it) {
        const int flat = (it * 256 + t) * 4;
        const int ii = flat >> 5, c = flat & 31;
        *(float4*)&Xs[flat] = *(const float4*)&X[(size_t)(i0 + ii) * 32 + c];
      }
    } else {
      const int flat = t * 4;
      const int ii = flat >> 4, c = flat & 15;
      *(float4*)&Xs[flat] = *(const float4*)&X[(size_t)(i0 + ii) * 16 + c];
    }
    __syncthreads();
    if (c0 < C) {
      #pragma unroll 8
      for (int ii = 0; ii < 64; ++ii) {
        const float a = adj[(size_t)(i0 + ii) * NROW + J0 + jl];
        const float4 xlo = *(const float4*)&Xs[ii * C + c0];
        const float4 xhi = *(const float4*)&Xs[ii * C + c0 + 4];
        acc[0] += a * xlo.x; acc[1] += a * xlo.y; acc[2] += a * xlo.z; acc[3] += a * xlo.w;
        acc[4] += a * xhi.x; acc[5] += a * xhi.y; acc[6] += a * xhi.z; acc[7] += a * xhi.w;
        if (SUMCOL && cg == 0) accCS += fabsf(a);
      }
    }
    __syncthreads();
  }
  if (c0 < C) {
    float4 lo = {acc[0], acc[1], acc[2], acc[3]};
    float4 hi = {acc[4], acc[5], acc[6], acc[7]};
    *(float4*)&Gp[((size_t)ks * NROW + J0 + jl) * 32 + c0] = lo;
    *(float4*)&Gp[((size_t)ks * NROW + J0 + jl) * 32 + c0 + 4] = hi;
  }
  if (SUMCOL && cg == 0) csP[(size_t)ks * NROW + J0 + jl] = accCS;
}

// ---------------- S1: fold pass1 (f64), build l1, v1, mean-l1 partials ----------------
// grid 256 (32 rows/block), block 256
__global__ __launch_bounds__(256) void k_s1(const float* __restrict__ Fp, const float* __restrict__ rsP,
                                            const float* __restrict__ Gp, const float* __restrict__ csP,
                                            const float* __restrict__ x,  const float* __restrict__ W1,
                                            const float* __restrict__ b1,
                                            float* __restrict__ rowsum, float* __restrict__ colsum,
                                            float* __restrict__ v1, float* __restrict__ mlp) {
  __shared__ float l1L[32 * 100];
  __shared__ float rsL[32], csL[32];
  const int t = threadIdx.x;
  const int n0 = blockIdx.x * 32;
  if (t < 32) {
    double s = 0.;
    for (int p = 0; p < 16; ++p) s += (double)rsP[(size_t)p * NROW + n0 + t];
    s = fmax(s, 1e-12);
    rowsum[n0 + t] = (float)s; rsL[t] = (float)s;
  } else if (t < 64) {
    const int r = t - 32;
    double s = 0.;
    for (int p = 0; p < 8; ++p) s += (double)csP[(size_t)p * NROW + n0 + r];
    s = fmax(s, 1e-12);
    colsum[n0 + r] = (float)s; csL[r] = (float)s;
  }
  __syncthreads();
  {
    const int r = t >> 3, c = (t & 7) * 4;
    const int n = n0 + r;
    double s[4] = {0., 0., 0., 0.};
    for (int p = 0; p < 16; ++p) {
      const float4 v = *(const float4*)&Fp[((size_t)p * NROW + n) * 32 + c];
      s[0] += v.x; s[1] += v.y; s[2] += v.z; s[3] += v.w;
    }
    const double rs = (double)rsL[r];
    #pragma unroll
    for (int q = 0; q < 4; ++q) l1L[r * 100 + c + q] = (float)(s[q] / rs);
    double sg[4] = {0., 0., 0., 0.};
    for (int p = 0; p < 8; ++p) {
      const float4 v = *(const float4*)&Gp[((size_t)p * NROW + n) * 32 + c];
      sg[0] += v.x; sg[1] += v.y; sg[2] += v.z; sg[3] += v.w;
    }
    const double cs = (double)csL[r];
    #pragma unroll
    for (int q = 0; q < 4; ++q) l1L[r * 100 + 32 + c + q] = (float)(sg[q] / cs);
    *(float4*)&l1L[r * 100 + 64 + c] = *(const float4*)&x[(size_t)n * 32 + c];
  }
  __syncthreads();
  if (t < 96) {
    double s = 0.;
    for (int r = 0; r < 32; ++r) s += (double)l1L[r * 100 + t];
    mlp[(size_t)blockIdx.x * 96 + t] = (float)s;
  }
  {
    const int r = t & 31, jg = t >> 5;
    const int n = n0 + r;
    double accv[4];
    #pragma unroll
    for (int jj = 0; jj < 4; ++jj) accv[jj] = (double)b1[4 * jg + jj];
    for (int k = 0; k < 96; k += 4) {
      const float4 lv = *(const float4*)&l1L[r * 100 + k];
      #pragma unroll
      for (int jj = 0; jj < 4; ++jj) {
        const float4 wv = *(const float4*)&W1[(size_t)(4 * jg + jj) * 96 + k];
        accv[jj] += (double)lv.x * wv.x + (double)lv.y * wv.y + (double)lv.z * wv.z + (double)lv.w * wv.w;
      }
    }
    #pragma unroll
    for (int jj = 0; jj < 4; ++jj) v1[(size_t)n * 32 + 4 * jg + jj] = (float)leakyd(accv[jj]);
  }
}

// ---------------- S2: u1 (f64) ----------------
__global__ void k_s2(const float* __restrict__ mlp, const float* __restrict__ uW1,
                     const float* __restrict__ ub1, float* __restrict__ u1) {
  __shared__ float ml[96];
  const int t = threadIdx.x;  // block 128
  if (t < 96) {
    double s = 0.;
    for (int b = 0; b < 256; ++b) s += (double)mlp[(size_t)b * 96 + t];
    ml[t] = (float)(s * (1.0 / 8192.0));
  }
  __syncthreads();
  if (t < 16) {
    double a = (double)ub1[t];
    for (int k = 0; k < 96; ++k) a += (double)ml[k] * (double)uW1[(size_t)t * 96 + k];
    u1[t] = (float)leakyd(a);
  }
}

// ---------------- S4: fold pass2 (f64), LSTM (f64), outputs ----------------
// grid 512 (16 rows/block), block 256
__global__ __launch_bounds__(256) void k_s4(const float* __restrict__ Fp, const float* __restrict__ Gp,
                                            const float* __restrict__ v1, const float* __restrict__ u1,
                                            const float* __restrict__ rowsum, const float* __restrict__ colsum,
                                            const float* __restrict__ Wih, const float* __restrict__ Whh,
                                            const float* __restrict__ bih, const float* __restrict__ bhh,
                                            const float* __restrict__ h_in, const float* __restrict__ c_in,
                                            float* __restrict__ out, float* __restrict__ v2,
                                            float* __restrict__ u2p) {
  __shared__ float vec[16 * 148];     // [u1(16) | Av1(32) | ATv1(32) | v1(32) | h(32)]
  __shared__ float rsL[16], csL[16];
  __shared__ float hoL[16 * 17];
  const int t = threadIdx.x;
  const int n0 = blockIdx.x * 16;
  if (t < 16) rsL[t] = rowsum[n0 + t];
  else if (t < 32) csL[t - 16] = colsum[n0 + t - 16];
  { const int r = t >> 4, k = t & 15; vec[r * 148 + k] = u1[k]; }
  __syncthreads();
  {
    const int r = t >> 4, q = t & 15;
    const int n = n0 + r;
    if (q < 8) {
      const int c = q * 4;
      double s[4] = {0., 0., 0., 0.};
      for (int p = 0; p < 16; ++p) {
        const float4 v = *(const float4*)&Fp[((size_t)p * NROW + n) * 32 + c];
        s[0] += v.x; s[1] += v.y; s[2] += v.z; s[3] += v.w;
      }
      const double rs = (double)rsL[r];
      #pragma unroll
      for (int q2 = 0; q2 < 4; ++q2) vec[r * 148 + 16 + c + q2] = (float)(s[q2] / rs);
      *(float4*)&vec[r * 148 + 80 + c] = *(const float4*)&v1[(size_t)n * 32 + c];
    } else {
      const int c = (q - 8) * 4;
      double s[4] = {0., 0., 0., 0.};
      for (int p = 0; p < 8; ++p) {
        const float4 v = *(const float4*)&Gp[((size_t)p * NROW + n) * 32 + c];
        s[0] += v.x; s[1] += v.y; s[2] += v.z; s[3] += v.w;
      }
      const double cs = (double)csL[r];
      #pragma unroll
      for (int q2 = 0; q2 < 4; ++q2) vec[r * 148 + 48 + c + q2] = (float)(s[q2] / cs);
      *(float4*)&vec[r * 148 + 112 + c] = *(const float4*)&h_in[(size_t)n * 32 + c];
    }
  }
  __syncthreads();
  const int r = t >> 4, jg = t & 15;
  const int n = n0 + r;
  double g4[2][4];
  #pragma unroll
  for (int jj = 0; jj < 2; ++jj) {
    const int j = jg * 2 + jj;
    #pragma unroll
    for (int g = 0; g < 4; ++g) g4[jj][g] = (double)bih[g * 32 + j] + (double)bhh[g * 32 + j];
  }
  #pragma unroll
  for (int chn = 0; chn < 3; ++chn) {
    float4 lv[12];
    #pragma unroll
    for (int w = 0; w < 12; ++w) lv[w] = *(const float4*)&vec[r * 148 + chn * 48 + w * 4];
    #pragma unroll
    for (int jj = 0; jj < 2; ++jj) {
      const int j = jg * 2 + jj;
      #pragma unroll
      for (int g = 0; g < 4; ++g) {
        const int row = g * 32 + j;
        double a = 0.;
        if (chn < 2) {
          #pragma unroll
          for (int w = 0; w < 12; ++w) {
            const float4 wv = *(const float4*)&Wih[(size_t)row * 112 + chn * 48 + w * 4];
            a += (double)lv[w].x * wv.x + (double)lv[w].y * wv.y + (double)lv[w].z * wv.z + (double)lv[w].w * wv.w;
          }
        } else {
          #pragma unroll
          for (int w = 0; w < 4; ++w) {
            const float4 wv = *(const float4*)&Wih[(size_t)row * 112 + 96 + w * 4];
            a += (double)lv[w].x * wv.x + (double)lv[w].y * wv.y + (double)lv[w].z * wv.z + (double)lv[w].w * wv.w;
          }
          #pragma unroll
          for (int w = 4; w < 12; ++w) {
            const float4 wv = *(const float4*)&Whh[(size_t)row * 32 + (w - 4) * 4];
            a += (double)lv[w].x * wv.x + (double)lv[w].y * wv.y + (double)lv[w].z * wv.z + (double)lv[w].w * wv.w;
          }
        }
        g4[jj][g] += a;
      }
    }
  }
  #pragma unroll
  for (int jj = 0; jj < 2; ++jj) {
    const int j = jg * 2 + jj;
    const double iv = g4[jj][0], fv = g4[jj][1], gv = g4[jj][2], ov = g4[jj][3];
    const double cv = (double)c_in[(size_t)n * 32 + j];
    const double cn = sigd(fv) * cv + sigd(iv) * tanh(gv);
    const double hn = sigd(ov) * tanh(cn);
    out[8192 + (size_t)n * 32 + j] = (float)hn;
    out[8192 + 262144 + (size_t)n * 32 + j] = (float)cn;
    if (j < 16) v2[(size_t)n * 16 + j] = (float)leakyd(hn);
    else hoL[r * 17 + (j - 16)] = (float)hn;
  }
  __syncthreads();
  if (t < 16) {
    double s = 0.;
    for (int r2 = 0; r2 < 16; ++r2) s += (double)hoL[r2 * 17 + t];
    u2p[(size_t)blockIdx.x * 16 + t] = (float)s;
  }
}

// ---------------- S5: u2 (f64) ----------------
__global__ void k_s5(const float* __restrict__ u2p, float* __restrict__ u2) {
  const int t = threadIdx.x;  // block 64
  if (t < 16) {
    double s = 0.;
    for (int b = 0; b < 512; ++b) s += (double)u2p[(size_t)b * 16 + t];
    u2[t] = (float)leakyd(s * (1.0 / 8192.0));
  }
}

// ---------------- S6: fold pass3 (f64), layer3 (f64), logits, gumbel-argmax ----------------
// grid 128 (64 rows/block), block 256
// RNG: JAX partitionable threefry (default since ~0.4.36/0.5.0):
//   per flat element m: (o0,o1) = threefry2x32(key, (hi=0, lo=m)); bits32 = o0 ^ o1.
// Fallback ladder if this variant mismatches: bits = o1, then bits = o0.
__global__ __launch_bounds__(256) void k_s6(const float* __restrict__ Fp, const float* __restrict__ Gp,
                                            const float* __restrict__ v2, const float* __restrict__ u2,
                                            const float* __restrict__ rowsum, const float* __restrict__ colsum,
                                            const float* __restrict__ W3, const float* __restrict__ b3,
                                            float* __restrict__ out) {
  __shared__ float l3L[64 * 68];
  __shared__ float w3L[192];
  __shared__ float b3L[3];
  __shared__ double lgL[64 * 4];
  __shared__ float rsL[64], csL[64];
  const int t = threadIdx.x;
  const int n0 = blockIdx.x * 64;
  if (t < 192) w3L[t] = W3[t];
  if (t < 3) b3L[t] = b3[t];
  if (t < 64) rsL[t] = rowsum[n0 + t];
  else if (t < 128) csL[t - 64] = colsum[n0 + t - 64];
  __syncthreads();
  {
    const int r = t >> 2, q = t & 3;
    const int n = n0 + r;
    if (q == 0) {
      #pragma unroll
      for (int cc = 0; cc < 4; ++cc) *(float4*)&l3L[r * 68 + cc * 4] = *(const float4*)&u2[cc * 4];
    } else if (q == 1) {
      const double rs = (double)rsL[r];
      #pragma unroll
      for (int cc = 0; cc < 4; ++cc) {
        const int c = cc * 4;
        double s[4] = {0., 0., 0., 0.};
        for (int p = 0; p < 16; ++p) {
          const float4 v = *(const float4*)&Fp[((size_t)p * NROW + n) * 32 + c];
          s[0] += v.x; s[1] += v.y; s[2] += v.z; s[3] += v.w;
        }
        #pragma unroll
        for (int q2 = 0; q2 < 4; ++q2) l3L[r * 68 + 16 + c + q2] = (float)(s[q2] / rs);
      }
    } else if (q == 2) {
      const double cs = (double)csL[r];
      #pragma unroll
      for (int cc = 0; cc < 4; ++cc) {
        const int c = cc * 4;
        double s[4] = {0., 0., 0., 0.};
        for (int p = 0; p < 8; ++p) {
          const float4 v = *(const float4*)&Gp[((size_t)p * NROW + n) * 32 + c];
          s[0] += v.x; s[1] += v.y; s[2] += v.z; s[3] += v.w;
        }
        #pragma unroll
        for (int q2 = 0; q2 < 4; ++q2) l3L[r * 68 + 32 + c + q2] = (float)(s[q2] / cs);
      }
    } else {
      #pragma unroll
      for (int cc = 0; cc < 4; ++cc)
        *(float4*)&l3L[r * 68 + 48 + cc * 4] = *(const float4*)&v2[(size_t)n * 16 + cc * 4];
    }
  }
  __syncthreads();
  {
    const int r = t >> 2, q = t & 3;
    if (q < 3) {
      double a = (double)b3L[q];
      for (int k = 0; k < 64; ++k) a += (double)l3L[r * 68 + k] * (double)w3L[q * 64 + k];
      lgL[r * 4 + q] = 2.0 * tanh(a);
    }
  }
  __syncthreads();
  if ((t & 3) == 0) {
    const int r = t >> 2;
    const int n = n0 + r;
    int best = 0;
    double bv = -1.0e300;
    #pragma unroll
    for (int j = 0; j < 3; ++j) {
      const uint32_t m = (uint32_t)(n * 3 + j);
      uint32_t o0, o1;
      threefry(0u, m, o0, o1);           // partitionable: counter64 = m -> (hi=0, lo=m)
      const uint32_t bits = o0 ^ o1;     // 32-bit output word
      const float f = __uint_as_float((bits >> 9) | 0x3f800000u) - 1.0f;
      const double u = fmax((double)f, 1.17549435e-38);
      const double g = -log(-log(u));
      const double val = g + lgL[r * 4 + j];
      if (val > bv) { bv = val; best = j; }
    }
    out[n] = (float)best - 1.0f;
  }
}

// ---------------- launch ----------------
extern "C" void kernel_launch(void* const* d_in, const int* in_sizes, int n_in,
                              void* d_out, int out_size, void* d_ws, size_t ws_size,
                              hipStream_t stream) {
  const float* adj = (const float*)d_in[0];
  const float* x   = (const float*)d_in[1];
  const float* h   = (const float*)d_in[2];
  const float* c   = (const float*)d_in[3];
  const float* W1  = (const float*)d_in[4];
  const float* b1  = (const float*)d_in[5];
  const float* uW1 = (const float*)d_in[6];
  const float* ub1 = (const float*)d_in[7];
  const float* Wih = (const float*)d_in[8];
  const float* Whh = (const float*)d_in[9];
  const float* bih = (const float*)d_in[10];
  const float* bhh = (const float*)d_in[11];
  const float* W3  = (const float*)d_in[12];
  const float* b3  = (const float*)d_in[13];
  float* out = (float*)d_out;
  float* ws  = (float*)d_ws;

  float* Fp  = ws + W_FP;
  float* Gp  = ws + W_GP;
  float* rsP = ws + W_RSP;
  float* csP = ws + W_CSP;
  float* rs  = ws + W_RS;
  float* cs  = ws + W_CS;
  float* v1  = ws + W_V1;
  float* v2  = ws + W_V2;
  float* u1  = ws + W_U1;
  float* u2  = ws + W_U2;
  float* mlp = ws + W_MLP;
  float* u2p = ws + W_U2P;

  // ---- pass 1: adj @ x, adj.T @ x (+ row/col sums) ----
  k_fwd<32, true><<<dim3(32, 16), 256, 0, stream>>>(adj, x, Fp, rsP);
  k_tr<32, true><<<dim3(128, 8), 256, 0, stream>>>(adj, x, Gp, csP);
  k_s1<<<256, 256, 0, stream>>>(Fp, rsP, Gp, csP, x, W1, b1, rs, cs, v1, mlp);
  k_s2<<<1, 128, 0, stream>>>(mlp, uW1, ub1, u1);

  // ---- pass 2: adj @ v1, adj.T @ v1 ; LSTM ----
  k_fwd<32, false><<<dim3(32, 16), 256, 0, stream>>>(adj, v1, Fp, nullptr);
  k_tr<32, false><<<dim3(128, 8), 256, 0, stream>>>(adj, v1, Gp, nullptr);
  k_s4<<<512, 256, 0, stream>>>(Fp, Gp, v1, u1, rs, cs, Wih, Whh, bih, bhh, h, c, out, v2, u2p);
  k_s5<<<1, 64, 0, stream>>>(u2p, u2);

  // ---- pass 3: adj @ v2, adj.T @ v2 ; layer3 + sampling ----
  k_fwd<16, false><<<dim3(32, 16), 256, 0, stream>>>(adj, v2, Fp, nullptr);
  k_tr<16, false><<<dim3(128, 8), 256, 0, stream>>>(adj, v2, Gp, nullptr);
  k_s6<<<128, 256, 0, stream>>>(Fp, Gp, v2, u2, rs, cs, W3, b3, out);
}